// Round 4
// baseline (17993.588 us; speedup 1.0000x reference)
//
#include <hip/hip_runtime.h>
#include <stdint.h>

#define T_STEPS 101
#define ROWS 1600
#define NTHR 512
#define G1  10      /* L1: 40 nz  = 10 groups of 4 */
#define G23 13      /* L2/3: 50 nz -> padded 52 = 13 groups */

/* ws byte offsets (all 16B aligned) */
#define W1V_OFF 0
#define W2V_OFF 256000
#define W3V_OFF 588800
#define W1C_OFF 921600
#define W2C_OFF 1049600
#define W3C_OFF 1216000

__device__ __forceinline__ float sigmoidf(float v) { return 1.0f / (1.0f + expf(-v)); }

// ---------------------------------------------------------------------------
// Prep: fixed-length CSR packed as float4 weight groups + uint2 col groups
// (4 u16 pre-scaled byte offsets per uint2). SoA [group][1600] for coalescing.
// L1 offsets scale x16 (float4 table rows), L2/3 scale x4 (u8 table rows).
// Padding entries have w=0, off=0 (fmaf(0,s,a)==a -> bitwise safe).
// ---------------------------------------------------------------------------
__global__ void prep_kernel(const float* __restrict__ W1, const float* __restrict__ W2,
                            const float* __restrict__ W3, uint8_t* __restrict__ ws) {
  int gid = blockIdx.x * blockDim.x + threadIdx.x;
  if (gid >= 3 * ROWS) return;
  int l = gid / ROWS, r = gid - l * ROWS;
  const float* W; int in_f, knz, G, scale; float4* wv; uint2* wc;
  if (l == 0)      { W = W1; in_f = 320; knz = 40; G = G1;  scale = 16;
                     wv = (float4*)(ws + W1V_OFF); wc = (uint2*)(ws + W1C_OFF); }
  else if (l == 1) { W = W2; in_f = 400; knz = 50; G = G23; scale = 4;
                     wv = (float4*)(ws + W2V_OFF); wc = (uint2*)(ws + W2C_OFF); }
  else             { W = W3; in_f = 400; knz = 50; G = G23; scale = 4;
                     wv = (float4*)(ws + W3V_OFF); wc = (uint2*)(ws + W3C_OFF); }
  float wl[52]; uint32_t cl[52];
  int cnt = 0;
  for (int col = 0; col < in_f; ++col) {
    float w = W[(size_t)r * in_f + col];
    if (w != 0.0f && cnt < knz) { wl[cnt] = w; cl[cnt] = (uint32_t)(col * scale); ++cnt; }
  }
  for (; cnt < G * 4; ++cnt) { wl[cnt] = 0.0f; cl[cnt] = 0u; }
  for (int g = 0; g < G; ++g) {
    wv[g * ROWS + r] = make_float4(wl[4*g], wl[4*g+1], wl[4*g+2], wl[4*g+3]);
    wc[g * ROWS + r] = make_uint2(cl[4*g] | (cl[4*g+1] << 16),
                                  cl[4*g+2] | (cl[4*g+3] << 16));
  }
}

// ---------------------------------------------------------------------------
template<int G> struct Buf { float4 w[G]; uint2 c[G]; };

template<int G>
__device__ __forceinline__ void load_buf(Buf<G>& b, const float4* __restrict__ vw,
                                         const uint2* __restrict__ vc, int r) {
#pragma unroll
  for (int g = 0; g < G; ++g) b.w[g] = vw[g * ROWS + r];
#pragma unroll
  for (int g = 0; g < G; ++g) b.c[g] = vc[g * ROWS + r];
}

__device__ __forceinline__ void acc_f32(float w, const uint8_t* p,
                                        float& a0, float& a1, float& a2, float& a3) {
  const float4 kv = *reinterpret_cast<const float4*>(p);
  a0 = fmaf(w, kv.x, a0); a1 = fmaf(w, kv.y, a1);
  a2 = fmaf(w, kv.z, a2); a3 = fmaf(w, kv.w, a3);
}
__device__ __forceinline__ void acc_u8(float w, const uint8_t* p,
                                       float& a0, float& a1, float& a2, float& a3) {
  const uint32_t q = *reinterpret_cast<const uint32_t*>(p);
  a0 = fmaf(w, (float)(q & 0xffu), a0);
  a1 = fmaf(w, (float)((q >> 8) & 0xffu), a1);
  a2 = fmaf(w, (float)((q >> 16) & 0xffu), a2);
  a3 = fmaf(w, (float)(q >> 24), a3);
}

// One row-slot: gather (ascending j, same order as verified round-1 kernel),
// d update, 8-branch shuffle sum, leader mem/spike update.
template<int G, bool F32>
__device__ __forceinline__ void slot_compute(
    const Buf<G>& b, int r, const uint8_t* __restrict__ ktab,
    const float* __restrict__ beta_l, const float* __restrict__ bias_l,
    const float* __restrict__ alpha_l,
    float (&dreg)[4], uint8_t (*s_l)[4], float (*mem_l)[4]) {
  float a0 = bias_l[r]; float a1 = a0, a2 = a0, a3 = a0;
#pragma unroll
  for (int g = 0; g < G; ++g) {
    const uint32_t lo = b.c[g].x, hi = b.c[g].y;
    if constexpr (F32) {
      acc_f32(b.w[g].x, ktab + (lo & 0xffffu), a0, a1, a2, a3);
      acc_f32(b.w[g].y, ktab + (lo >> 16),     a0, a1, a2, a3);
      acc_f32(b.w[g].z, ktab + (hi & 0xffffu), a0, a1, a2, a3);
      acc_f32(b.w[g].w, ktab + (hi >> 16),     a0, a1, a2, a3);
    } else {
      acc_u8(b.w[g].x, ktab + (lo & 0xffffu), a0, a1, a2, a3);
      acc_u8(b.w[g].y, ktab + (lo >> 16),     a0, a1, a2, a3);
      acc_u8(b.w[g].z, ktab + (hi & 0xffffu), a0, a1, a2, a3);
      acc_u8(b.w[g].w, ktab + (hi >> 16),     a0, a1, a2, a3);
    }
  }
  const float bt = beta_l[r], ob = 1.0f - bt;
  float d0 = fmaf(bt, dreg[0], ob * a0);
  float d1 = fmaf(bt, dreg[1], ob * a1);
  float d2 = fmaf(bt, dreg[2], ob * a2);
  float d3 = fmaf(bt, dreg[3], ob * a3);
  dreg[0] = d0; dreg[1] = d1; dreg[2] = d2; dreg[3] = d3;
  d0 += __shfl_xor(d0, 1); d0 += __shfl_xor(d0, 2); d0 += __shfl_xor(d0, 4);
  d1 += __shfl_xor(d1, 1); d1 += __shfl_xor(d1, 2); d1 += __shfl_xor(d1, 4);
  d2 += __shfl_xor(d2, 1); d2 += __shfl_xor(d2, 2); d2 += __shfl_xor(d2, 4);
  d3 += __shfl_xor(d3, 1); d3 += __shfl_xor(d3, 2); d3 += __shfl_xor(d3, 4);
  if ((threadIdx.x & 7) == 0) {
    const int n = r >> 3;
    const float al = alpha_l[n], oa = 1.0f - al;
    float4 mv = *reinterpret_cast<float4*>(&mem_l[n][0]);
    const uint32_t so = *reinterpret_cast<uint32_t*>(&s_l[n][0]);
    const float m0 = fmaf(mv.x - (float)(so & 0xffu),         al, oa * d0);
    const float m1 = fmaf(mv.y - (float)((so >> 8) & 0xffu),  al, oa * d1);
    const float m2 = fmaf(mv.z - (float)((so >> 16) & 0xffu), al, oa * d2);
    const float m3 = fmaf(mv.w - (float)(so >> 24),           al, oa * d3);
    *reinterpret_cast<float4*>(&mem_l[n][0]) = make_float4(m0, m1, m2, m3);
    const uint32_t sn = (m0 > 1.0f ? 1u : 0u) | (m1 > 1.0f ? 0x100u : 0u)
                      | (m2 > 1.0f ? 0x10000u : 0u) | (m3 > 1.0f ? 0x1000000u : 0u);
    *reinterpret_cast<uint32_t*>(&s_l[n][0]) = sn;
  }
}

// Layer phase with slot-level software pipeline. Slots 0..2 by all threads,
// extra slot (rows 1536-1599) by wave LW (rotates per layer to balance).
template<int G, bool F32, int LW>
__device__ __forceinline__ void layer_phase(
    int tid, int wv, const float4* __restrict__ vw, const uint2* __restrict__ vc,
    const uint8_t* __restrict__ ktab,
    const float* __restrict__ beta_l, const float* __restrict__ bias_l,
    const float* __restrict__ alpha_l,
    float (&dA)[4], float (&dB)[4], float (&dC)[4], float (&dX)[4],
    uint8_t (*s_l)[4], float (*mem_l)[4]) {
  Buf<G> A, B;
  load_buf<G>(A, vw, vc, tid);
  load_buf<G>(B, vw, vc, tid + 512);
  slot_compute<G, F32>(A, tid, ktab, beta_l, bias_l, alpha_l, dA, s_l, mem_l);
  load_buf<G>(A, vw, vc, tid + 1024);
  slot_compute<G, F32>(B, tid + 512, ktab, beta_l, bias_l, alpha_l, dB, s_l, mem_l);
  const int r3 = 1536 + (tid & 63);
  if (wv == LW) load_buf<G>(B, vw, vc, r3);
  slot_compute<G, F32>(A, tid + 1024, ktab, beta_l, bias_l, alpha_l, dC, s_l, mem_l);
  if (wv == LW) slot_compute<G, F32>(B, r3, ktab, beta_l, bias_l, alpha_l, dX, s_l, mem_l);
}

// ---------------------------------------------------------------------------
// Main kernel: 256 blocks x 512 threads, 4 batches/block (round-1 dataflow,
// restructured for ILP: register-preloaded weight slots, constants in LDS).
// ---------------------------------------------------------------------------
__global__ void __launch_bounds__(NTHR, 2)
snn_main(const float* __restrict__ x,
         const float* __restrict__ b1, const float* __restrict__ tm1, const float* __restrict__ tn1,
         const float* __restrict__ b2, const float* __restrict__ tm2, const float* __restrict__ tn2,
         const float* __restrict__ b3, const float* __restrict__ tm3, const float* __restrict__ tn3,
         const float* __restrict__ W4, const float* __restrict__ b4, const float* __restrict__ tm4,
         const float4* __restrict__ w1v, const uint2* __restrict__ w1c,
         const float4* __restrict__ w2v, const uint2* __restrict__ w2c,
         const float4* __restrict__ w3v, const uint2* __restrict__ w3c,
         float* __restrict__ out)
{
  __shared__ __align__(16) float   k1f[320][4];       // L1 input (x f32 + s1-as-f32)
  __shared__ __align__(4)  uint8_t k23[400][4];       // L2/3 input (binary spikes u8)
  __shared__ __align__(4)  uint8_t s_lds[3][200][4];
  __shared__ __align__(16) float   mem_lds[3][200][4];
  __shared__ float w4_lds[12][201];
  __shared__ float beta_lds[3][ROWS];
  __shared__ float bias_lds[3][ROWS];
  __shared__ float alpha_lds[3][200];

  const int tid = threadIdx.x;
  const int wv  = tid >> 6;
  const int bg  = blockIdx.x;

  for (int idx = tid; idx < 3 * 200; idx += NTHR) {
    reinterpret_cast<uint32_t*>(&s_lds[0][0][0])[idx] = 0u;
    reinterpret_cast<float4*>(&mem_lds[0][0][0])[idx] = make_float4(0.f, 0.f, 0.f, 0.f);
  }
  for (int idx = tid; idx < 12 * 200; idx += NTHR)
    w4_lds[idx / 200][idx % 200] = W4[idx];
  for (int idx = tid; idx < ROWS; idx += NTHR) {
    beta_lds[0][idx] = sigmoidf(tn1[idx]); bias_lds[0][idx] = b1[idx];
    beta_lds[1][idx] = sigmoidf(tn2[idx]); bias_lds[1][idx] = b2[idx];
    beta_lds[2][idx] = sigmoidf(tn3[idx]); bias_lds[2][idx] = b3[idx];
  }
  if (tid < 200) {
    alpha_lds[0][tid] = sigmoidf(tm1[tid]);
    alpha_lds[1][tid] = sigmoidf(tm2[tid]);
    alpha_lds[2][tid] = sigmoidf(tm3[tid]);
  }

  float d_[3][3][4], dX[4];
#pragma unroll
  for (int l = 0; l < 3; ++l)
#pragma unroll
    for (int i = 0; i < 3; ++i)
#pragma unroll
      for (int b = 0; b < 4; ++b) d_[l][i][b] = 0.0f;
#pragma unroll
  for (int b = 0; b < 4; ++b) dX[b] = 0.0f;

  float m4_reg = 0.0f, m4_acc = 0.0f, a4 = 0.0f, b4r = 0.0f;
  if (tid < 48) { const int o = tid >> 2; a4 = sigmoidf(tm4[o]); b4r = b4[o]; }
  __syncthreads();

  const uint8_t* k1b = reinterpret_cast<const uint8_t*>(&k1f[0][0]);
  const uint8_t* k2b = reinterpret_cast<const uint8_t*>(&k23[0][0]);

  for (int t = 0; t < T_STEPS; ++t) {
    // ---- stage k1 = [x_t | s1(old) as f32] ----------------------------
    if (tid < 480) {
      const int bat = tid / 120, cf = tid - bat * 120;
      const int c = cf / 40, f = cf - c * 40;
      const int b = bg * 4 + bat;
      k1f[cf][bat] = x[(((size_t)b * 3 + c) * T_STEPS + t) * 40 + f];
    }
    if (tid < 200) {
      const uint32_t so = reinterpret_cast<const uint32_t*>(&s_lds[0][0][0])[tid];
      *reinterpret_cast<float4*>(&k1f[120 + tid][0]) =
          make_float4((float)(so & 0xffu), (float)((so >> 8) & 0xffu),
                      (float)((so >> 16) & 0xffu), (float)(so >> 24));
    }
    __syncthreads();
    layer_phase<G1, true, 1>(tid, wv, w1v, w1c, k1b,
                             beta_lds[0], bias_lds[0], alpha_lds[0],
                             d_[0][0], d_[0][1], d_[0][2], dX, s_lds[0], mem_lds[0]);
    __syncthreads();
    // ---- stage k2 = [s1(new) | s2(old)] -------------------------------
    if (tid < 200)
      reinterpret_cast<uint32_t*>(&k23[0][0])[tid] =
          reinterpret_cast<const uint32_t*>(&s_lds[0][0][0])[tid];
    else if (tid < 400)
      reinterpret_cast<uint32_t*>(&k23[0][0])[tid] =
          reinterpret_cast<const uint32_t*>(&s_lds[1][0][0])[tid - 200];
    __syncthreads();
    layer_phase<G23, false, 2>(tid, wv, w2v, w2c, k2b,
                               beta_lds[1], bias_lds[1], alpha_lds[1],
                               d_[1][0], d_[1][1], d_[1][2], dX, s_lds[1], mem_lds[1]);
    __syncthreads();
    // ---- stage k3 = [s2(new) | s3(old)] -------------------------------
    if (tid < 200)
      reinterpret_cast<uint32_t*>(&k23[0][0])[tid] =
          reinterpret_cast<const uint32_t*>(&s_lds[1][0][0])[tid];
    else if (tid < 400)
      reinterpret_cast<uint32_t*>(&k23[0][0])[tid] =
          reinterpret_cast<const uint32_t*>(&s_lds[2][0][0])[tid - 200];
    __syncthreads();
    layer_phase<G23, false, 3>(tid, wv, w3v, w3c, k2b,
                               beta_lds[2], bias_lds[2], alpha_lds[2],
                               d_[2][0], d_[2][1], d_[2][2], dX, s_lds[2], mem_lds[2]);
    __syncthreads();
    // ---- leaky readout (wave 0; overlaps next step's staging) ---------
    if (tid < 48) {
      const int o = tid >> 2, bat = tid & 3;
      float dot = b4r;
#pragma unroll 8
      for (int n = 0; n < 200; ++n)
        dot = fmaf(w4_lds[o][n], (float)s_lds[2][n][bat], dot);
      m4_reg = a4 * m4_reg + (1.0f - a4) * dot;
      m4_acc += m4_reg;
    }
    // no trailing barrier: stage-k1(t+1) touches only k1f / s_lds[0]
  }

  // ---- log_softmax(acc / T) -------------------------------------------
  __syncthreads();
  if (tid < 48) {
    const int o = tid >> 2, bat = tid & 3;
    k1f[o][bat] = m4_acc * (1.0f / (float)T_STEPS);
  }
  __syncthreads();
  if (tid < 4) {
    const int bat = tid;
    float v[12], mx = -1e30f;
#pragma unroll
    for (int o = 0; o < 12; ++o) { v[o] = k1f[o][bat]; mx = fmaxf(mx, v[o]); }
    float s = 0.0f;
#pragma unroll
    for (int o = 0; o < 12; ++o) s += expf(v[o] - mx);
    const float ls = logf(s);
#pragma unroll
    for (int o = 0; o < 12; ++o)
      out[((size_t)(bg * 4 + bat)) * 12 + o] = v[o] - mx - ls;
  }
}

// ---------------------------------------------------------------------------
extern "C" void kernel_launch(void* const* d_in, const int* in_sizes, int n_in,
                              void* d_out, int out_size, void* d_ws, size_t ws_size,
                              hipStream_t stream) {
  (void)in_sizes; (void)n_in; (void)out_size; (void)ws_size;
  const float* x   = (const float*)d_in[0];
  const float* W1  = (const float*)d_in[1];
  const float* b1  = (const float*)d_in[2];
  const float* tm1 = (const float*)d_in[3];
  const float* tn1 = (const float*)d_in[4];
  const float* W2  = (const float*)d_in[5];
  const float* b2  = (const float*)d_in[6];
  const float* tm2 = (const float*)d_in[7];
  const float* tn2 = (const float*)d_in[8];
  const float* W3  = (const float*)d_in[9];
  const float* b3  = (const float*)d_in[10];
  const float* tm3 = (const float*)d_in[11];
  const float* tn3 = (const float*)d_in[12];
  const float* W4  = (const float*)d_in[13];
  const float* b4  = (const float*)d_in[14];
  const float* tm4 = (const float*)d_in[15];

  uint8_t* ws = (uint8_t*)d_ws;
  const float4* w1v = (const float4*)(ws + W1V_OFF);
  const float4* w2v = (const float4*)(ws + W2V_OFF);
  const float4* w3v = (const float4*)(ws + W3V_OFF);
  const uint2*  w1c = (const uint2*)(ws + W1C_OFF);
  const uint2*  w2c = (const uint2*)(ws + W2C_OFF);
  const uint2*  w3c = (const uint2*)(ws + W3C_OFF);

  prep_kernel<<<dim3(19), dim3(256), 0, stream>>>(W1, W2, W3, ws);
  snn_main<<<dim3(256), dim3(NTHR), 0, stream>>>(
      x, b1, tm1, tn1, b2, tm2, tn2, b3, tm3, tn3, W4, b4, tm4,
      w1v, w1c, w2v, w2c, w3v, w3c, (float*)d_out);
}

// Round 5
// 15923.749 us; speedup vs baseline: 1.1300x; 1.1300x over previous
//
#include <hip/hip_runtime.h>
#include <stdint.h>

#define T_STEPS 101
#define ROWS 1600
#define NTHR 1024
#define G1  10      /* L1: 40 nz  = 10 groups of 4 */
#define G23 13      /* L2/3: 50 nz -> padded 52 = 13 groups */

/* ws byte offsets (all 16B aligned) */
#define W1V_OFF 0
#define W2V_OFF 256000
#define W3V_OFF 588800
#define W1C_OFF 921600
#define W2C_OFF 1049600
#define W3C_OFF 1216000

__device__ __forceinline__ float sigmoidf(float v) { return 1.0f / (1.0f + expf(-v)); }

// ---------------------------------------------------------------------------
// Prep: fixed-length CSR packed as float4 weight groups + uint2 col groups
// (4 u16 pre-scaled byte offsets per uint2). SoA [group][1600] for coalescing.
// L1 offsets scale x16 (float4 table rows), L2/3 scale x4 (u8 table rows).
// Padding entries have w=0, off=0 (fmaf(0,s,a)==a -> bitwise safe).
// Ascending col order == round-1's verified op order.
// ---------------------------------------------------------------------------
__global__ void prep_kernel(const float* __restrict__ W1, const float* __restrict__ W2,
                            const float* __restrict__ W3, uint8_t* __restrict__ ws) {
  int gid = blockIdx.x * blockDim.x + threadIdx.x;
  if (gid >= 3 * ROWS) return;
  int l = gid / ROWS, r = gid - l * ROWS;
  const float* W; int in_f, knz, G, scale; float4* wv; uint2* wc;
  if (l == 0)      { W = W1; in_f = 320; knz = 40; G = G1;  scale = 16;
                     wv = (float4*)(ws + W1V_OFF); wc = (uint2*)(ws + W1C_OFF); }
  else if (l == 1) { W = W2; in_f = 400; knz = 50; G = G23; scale = 4;
                     wv = (float4*)(ws + W2V_OFF); wc = (uint2*)(ws + W2C_OFF); }
  else             { W = W3; in_f = 400; knz = 50; G = G23; scale = 4;
                     wv = (float4*)(ws + W3V_OFF); wc = (uint2*)(ws + W3C_OFF); }
  float wl[52]; uint32_t cl[52];
  int cnt = 0;
  for (int col = 0; col < in_f; ++col) {
    float w = W[(size_t)r * in_f + col];
    if (w != 0.0f && cnt < knz) { wl[cnt] = w; cl[cnt] = (uint32_t)(col * scale); ++cnt; }
  }
  for (; cnt < G * 4; ++cnt) { wl[cnt] = 0.0f; cl[cnt] = 0u; }
  for (int g = 0; g < G; ++g) {
    wv[g * ROWS + r] = make_float4(wl[4*g], wl[4*g+1], wl[4*g+2], wl[4*g+3]);
    wc[g * ROWS + r] = make_uint2(cl[4*g] | (cl[4*g+1] << 16),
                                  cl[4*g+2] | (cl[4*g+3] << 16));
  }
}

// ---------------------------------------------------------------------------
__device__ __forceinline__ void acc_f32(float w, const uint8_t* p,
                                        float& a0, float& a1, float& a2, float& a3) {
  const float4 kv = *reinterpret_cast<const float4*>(p);
  a0 = fmaf(w, kv.x, a0); a1 = fmaf(w, kv.y, a1);
  a2 = fmaf(w, kv.z, a2); a3 = fmaf(w, kv.w, a3);
}
__device__ __forceinline__ void acc_u8(float w, const uint8_t* p,
                                       float& a0, float& a1, float& a2, float& a3) {
  const uint32_t q = *reinterpret_cast<const uint32_t*>(p);
  a0 = fmaf(w, (float)(q & 0xffu), a0);
  a1 = fmaf(w, (float)((q >> 8) & 0xffu), a1);
  a2 = fmaf(w, (float)((q >> 16) & 0xffu), a2);
  a3 = fmaf(w, (float)(q >> 24), a3);
}

// One row-slot: packed gather (ascending j, round-1 op order), d update,
// 8-branch shuffle sum, leader mem/spike update. Loop-local registers only
// (~30 live) -- the 13 group loads are address-independent so the compiler
// can issue them ahead for ILP without any explicit double buffer.
template<int G, bool F32>
__device__ __forceinline__ void slot_compute(
    int r, const float4* __restrict__ vw, const uint2* __restrict__ vc,
    const uint8_t* __restrict__ ktab,
    float bt, float bias, float al,
    float (&dreg)[4], uint8_t (*s_l)[4], float (*mem_l)[4])
{
  float a0 = bias, a1 = bias, a2 = bias, a3 = bias;
  const float4* vwr = vw + r;
  const uint2*  vcr = vc + r;
#pragma unroll
  for (int g = 0; g < G; ++g) {
    const float4 w = vwr[g * ROWS];
    const uint2  c = vcr[g * ROWS];
    if constexpr (F32) {
      acc_f32(w.x, ktab + (c.x & 0xffffu), a0, a1, a2, a3);
      acc_f32(w.y, ktab + (c.x >> 16),     a0, a1, a2, a3);
      acc_f32(w.z, ktab + (c.y & 0xffffu), a0, a1, a2, a3);
      acc_f32(w.w, ktab + (c.y >> 16),     a0, a1, a2, a3);
    } else {
      acc_u8(w.x, ktab + (c.x & 0xffffu), a0, a1, a2, a3);
      acc_u8(w.y, ktab + (c.x >> 16),     a0, a1, a2, a3);
      acc_u8(w.z, ktab + (c.y & 0xffffu), a0, a1, a2, a3);
      acc_u8(w.w, ktab + (c.y >> 16),     a0, a1, a2, a3);
    }
  }
  const float ob = 1.0f - bt;
  float d0 = fmaf(bt, dreg[0], ob * a0);
  float d1 = fmaf(bt, dreg[1], ob * a1);
  float d2 = fmaf(bt, dreg[2], ob * a2);
  float d3 = fmaf(bt, dreg[3], ob * a3);
  dreg[0] = d0; dreg[1] = d1; dreg[2] = d2; dreg[3] = d3;
  d0 += __shfl_xor(d0, 1); d0 += __shfl_xor(d0, 2); d0 += __shfl_xor(d0, 4);
  d1 += __shfl_xor(d1, 1); d1 += __shfl_xor(d1, 2); d1 += __shfl_xor(d1, 4);
  d2 += __shfl_xor(d2, 1); d2 += __shfl_xor(d2, 2); d2 += __shfl_xor(d2, 4);
  d3 += __shfl_xor(d3, 1); d3 += __shfl_xor(d3, 2); d3 += __shfl_xor(d3, 4);
  if ((threadIdx.x & 7) == 0) {
    const int n = r >> 3;
    const float oa = 1.0f - al;
    float4 mv = *reinterpret_cast<float4*>(&mem_l[n][0]);
    const uint32_t so = *reinterpret_cast<uint32_t*>(&s_l[n][0]);
    const float m0 = fmaf(mv.x - (float)(so & 0xffu),         al, oa * d0);
    const float m1 = fmaf(mv.y - (float)((so >> 8) & 0xffu),  al, oa * d1);
    const float m2 = fmaf(mv.z - (float)((so >> 16) & 0xffu), al, oa * d2);
    const float m3 = fmaf(mv.w - (float)(so >> 24),           al, oa * d3);
    *reinterpret_cast<float4*>(&mem_l[n][0]) = make_float4(m0, m1, m2, m3);
    const uint32_t sn = (m0 > 1.0f ? 1u : 0u) | (m1 > 1.0f ? 0x100u : 0u)
                      | (m2 > 1.0f ? 0x10000u : 0u) | (m3 > 1.0f ? 0x1000000u : 0u);
    *reinterpret_cast<uint32_t*>(&s_l[n][0]) = sn;
  }
}

// ---------------------------------------------------------------------------
// Main kernel: 256 blocks x 1024 threads (16 waves/CU), 4 batches/block.
// Row slots: slot0 r=tid (rows 0..1023); slot1 r=1024+tid for tid<576.
// Max 2 slots/thread (round 1: 4 on the critical wave) + 2x latency hiding.
// ---------------------------------------------------------------------------
__global__ void __launch_bounds__(NTHR)
snn_main(const float* __restrict__ x,
         const float* __restrict__ b1, const float* __restrict__ tm1, const float* __restrict__ tn1,
         const float* __restrict__ b2, const float* __restrict__ tm2, const float* __restrict__ tn2,
         const float* __restrict__ b3, const float* __restrict__ tm3, const float* __restrict__ tn3,
         const float* __restrict__ W4, const float* __restrict__ b4, const float* __restrict__ tm4,
         const float4* __restrict__ w1v, const uint2* __restrict__ w1c,
         const float4* __restrict__ w2v, const uint2* __restrict__ w2c,
         const float4* __restrict__ w3v, const uint2* __restrict__ w3c,
         float* __restrict__ out)
{
  __shared__ __align__(16) float   k1f[320][4];       // L1 input (x f32 + s1-as-f32)
  __shared__ __align__(4)  uint8_t k23[400][4];       // L2/3 input (binary spikes u8)
  __shared__ __align__(4)  uint8_t s_lds[3][200][4];
  __shared__ __align__(16) float   mem_lds[3][200][4];
  __shared__ float w4_lds[12][201];

  const int tid = threadIdx.x;
  const int bg  = blockIdx.x;

  for (int idx = tid; idx < 3 * 200; idx += NTHR) {
    reinterpret_cast<uint32_t*>(&s_lds[0][0][0])[idx] = 0u;
    reinterpret_cast<float4*>(&mem_lds[0][0][0])[idx] = make_float4(0.f, 0.f, 0.f, 0.f);
  }
  for (int idx = tid; idx < 12 * 200; idx += NTHR)
    w4_lds[idx / 200][idx % 200] = W4[idx];

  // per-thread constants for 2 slots x 3 layers (slot1 clamped for tid>=576)
  const int r0 = tid;
  const int r1 = 1024 + (tid < 576 ? tid : 0);
  float beta_[3][2], bias_[3][2], alpha_[3][2];
  beta_[0][0] = sigmoidf(tn1[r0]); bias_[0][0] = b1[r0]; alpha_[0][0] = sigmoidf(tm1[r0 >> 3]);
  beta_[0][1] = sigmoidf(tn1[r1]); bias_[0][1] = b1[r1]; alpha_[0][1] = sigmoidf(tm1[r1 >> 3]);
  beta_[1][0] = sigmoidf(tn2[r0]); bias_[1][0] = b2[r0]; alpha_[1][0] = sigmoidf(tm2[r0 >> 3]);
  beta_[1][1] = sigmoidf(tn2[r1]); bias_[1][1] = b2[r1]; alpha_[1][1] = sigmoidf(tm2[r1 >> 3]);
  beta_[2][0] = sigmoidf(tn3[r0]); bias_[2][0] = b3[r0]; alpha_[2][0] = sigmoidf(tm3[r0 >> 3]);
  beta_[2][1] = sigmoidf(tn3[r1]); bias_[2][1] = b3[r1]; alpha_[2][1] = sigmoidf(tm3[r1 >> 3]);

  float d_[3][2][4];
#pragma unroll
  for (int l = 0; l < 3; ++l)
#pragma unroll
    for (int i = 0; i < 2; ++i)
#pragma unroll
      for (int b = 0; b < 4; ++b) d_[l][i][b] = 0.0f;

  // x staging addresses hoisted out of the T-loop
  const float* xp = nullptr; float* kdst = nullptr;
  if (tid < 480) {
    const int bat = tid / 120, cf = tid - bat * 120;
    const int c = cf / 40, f = cf - c * 40;
    xp = x + (((size_t)(bg * 4 + bat) * 3 + c) * T_STEPS) * 40 + f;
    kdst = &k1f[cf][bat];
  }

  float m4_reg = 0.0f, m4_acc = 0.0f, a4 = 0.0f, b4r = 0.0f;
  if (tid < 48) { const int o = tid >> 2; a4 = sigmoidf(tm4[o]); b4r = b4[o]; }
  __syncthreads();

  const uint8_t* k1b = reinterpret_cast<const uint8_t*>(&k1f[0][0]);
  const uint8_t* k2b = reinterpret_cast<const uint8_t*>(&k23[0][0]);

  for (int t = 0; t < T_STEPS; ++t) {
    // ---- stage k1 = [x_t | s1(old) as f32] ----------------------------
    if (tid < 480) *kdst = xp[t * 40];
    if (tid < 200) {
      const uint32_t so = reinterpret_cast<const uint32_t*>(&s_lds[0][0][0])[tid];
      *reinterpret_cast<float4*>(&k1f[120 + tid][0]) =
          make_float4((float)(so & 0xffu), (float)((so >> 8) & 0xffu),
                      (float)((so >> 16) & 0xffu), (float)(so >> 24));
    }
    __syncthreads();
    slot_compute<G1, true>(r0, w1v, w1c, k1b, beta_[0][0], bias_[0][0], alpha_[0][0],
                           d_[0][0], s_lds[0], mem_lds[0]);
    if (tid < 576)
      slot_compute<G1, true>(r1, w1v, w1c, k1b, beta_[0][1], bias_[0][1], alpha_[0][1],
                             d_[0][1], s_lds[0], mem_lds[0]);
    __syncthreads();
    // ---- stage k2 = [s1(new) | s2(old)] -------------------------------
    if (tid < 200)
      reinterpret_cast<uint32_t*>(&k23[0][0])[tid] =
          reinterpret_cast<const uint32_t*>(&s_lds[0][0][0])[tid];
    else if (tid < 400)
      reinterpret_cast<uint32_t*>(&k23[0][0])[tid] =
          reinterpret_cast<const uint32_t*>(&s_lds[1][0][0])[tid - 200];
    __syncthreads();
    slot_compute<G23, false>(r0, w2v, w2c, k2b, beta_[1][0], bias_[1][0], alpha_[1][0],
                             d_[1][0], s_lds[1], mem_lds[1]);
    if (tid < 576)
      slot_compute<G23, false>(r1, w2v, w2c, k2b, beta_[1][1], bias_[1][1], alpha_[1][1],
                               d_[1][1], s_lds[1], mem_lds[1]);
    __syncthreads();
    // ---- stage k3 = [s2(new) | s3(old)] -------------------------------
    if (tid < 200)
      reinterpret_cast<uint32_t*>(&k23[0][0])[tid] =
          reinterpret_cast<const uint32_t*>(&s_lds[1][0][0])[tid];
    else if (tid < 400)
      reinterpret_cast<uint32_t*>(&k23[0][0])[tid] =
          reinterpret_cast<const uint32_t*>(&s_lds[2][0][0])[tid - 200];
    __syncthreads();
    slot_compute<G23, false>(r0, w3v, w3c, k2b, beta_[2][0], bias_[2][0], alpha_[2][0],
                             d_[2][0], s_lds[2], mem_lds[2]);
    if (tid < 576)
      slot_compute<G23, false>(r1, w3v, w3c, k2b, beta_[2][1], bias_[2][1], alpha_[2][1],
                               d_[2][1], s_lds[2], mem_lds[2]);
    __syncthreads();
    // ---- leaky readout (tid<48; overlaps next step's staging) ---------
    if (tid < 48) {
      const int o = tid >> 2, bat = tid & 3;
      float dot = b4r;
#pragma unroll 8
      for (int n = 0; n < 200; ++n)
        dot = fmaf(w4_lds[o][n], (float)s_lds[2][n][bat], dot);
      m4_reg = a4 * m4_reg + (1.0f - a4) * dot;
      m4_acc += m4_reg;
    }
    // no trailing barrier: stage-k1(t+1) touches only k1f / s_lds[0]
  }

  // ---- log_softmax(acc / T) -------------------------------------------
  __syncthreads();
  if (tid < 48) {
    const int o = tid >> 2, bat = tid & 3;
    k1f[o][bat] = m4_acc * (1.0f / (float)T_STEPS);
  }
  __syncthreads();
  if (tid < 4) {
    const int bat = tid;
    float v[12], mx = -1e30f;
#pragma unroll
    for (int o = 0; o < 12; ++o) { v[o] = k1f[o][bat]; mx = fmaxf(mx, v[o]); }
    float s = 0.0f;
#pragma unroll
    for (int o = 0; o < 12; ++o) s += expf(v[o] - mx);
    const float ls = logf(s);
#pragma unroll
    for (int o = 0; o < 12; ++o)
      out[((size_t)(bg * 4 + bat)) * 12 + o] = v[o] - mx - ls;
  }
}

// ---------------------------------------------------------------------------
extern "C" void kernel_launch(void* const* d_in, const int* in_sizes, int n_in,
                              void* d_out, int out_size, void* d_ws, size_t ws_size,
                              hipStream_t stream) {
  (void)in_sizes; (void)n_in; (void)out_size; (void)ws_size;
  const float* x   = (const float*)d_in[0];
  const float* W1  = (const float*)d_in[1];
  const float* b1  = (const float*)d_in[2];
  const float* tm1 = (const float*)d_in[3];
  const float* tn1 = (const float*)d_in[4];
  const float* W2  = (const float*)d_in[5];
  const float* b2  = (const float*)d_in[6];
  const float* tm2 = (const float*)d_in[7];
  const float* tn2 = (const float*)d_in[8];
  const float* W3  = (const float*)d_in[9];
  const float* b3  = (const float*)d_in[10];
  const float* tm3 = (const float*)d_in[11];
  const float* tn3 = (const float*)d_in[12];
  const float* W4  = (const float*)d_in[13];
  const float* b4  = (const float*)d_in[14];
  const float* tm4 = (const float*)d_in[15];

  uint8_t* ws = (uint8_t*)d_ws;
  const float4* w1v = (const float4*)(ws + W1V_OFF);
  const float4* w2v = (const float4*)(ws + W2V_OFF);
  const float4* w3v = (const float4*)(ws + W3V_OFF);
  const uint2*  w1c = (const uint2*)(ws + W1C_OFF);
  const uint2*  w2c = (const uint2*)(ws + W2C_OFF);
  const uint2*  w3c = (const uint2*)(ws + W3C_OFF);

  prep_kernel<<<dim3(19), dim3(256), 0, stream>>>(W1, W2, W3, ws);
  snn_main<<<dim3(256), dim3(NTHR), 0, stream>>>(
      x, b1, tm1, tn1, b2, tm2, tn2, b3, tm3, tn3, W4, b4, tm4,
      w1v, w1c, w2v, w2c, w3v, w3c, (float*)d_out);
}